// Round 7
// baseline (348.793 us; speedup 1.0000x reference)
//
#include <hip/hip_runtime.h>

#define BATCH 4
#define CCH 256
#define NN 4096
#define CQ 64

typedef __bf16 bf16;
typedef __bf16 bf16x4 __attribute__((ext_vector_type(4)));
typedef __bf16 bf16x8 __attribute__((ext_vector_type(8)));
typedef float f32x4 __attribute__((ext_vector_type(4)));

static __device__ __forceinline__ f32x4 mfma16(bf16x8 a, bf16x8 b, f32x4 c) {
  return __builtin_amdgcn_mfma_f32_16x16x32_bf16(a, b, c, 0, 0, 0);
}

// ---------------- prep: convert weights to bf16 ----------------
__global__ __launch_bounds__(256) void prep_kernel(const float* __restrict__ w_qk,
                                                   const float* __restrict__ w_v,
                                                   const float* __restrict__ w_trans,
                                                   bf16* __restrict__ wkvb,
                                                   bf16* __restrict__ wtb) {
  int i = blockIdx.x * 256 + threadIdx.x;
  if (i < 320 * 256) {
    int r = i >> 8, c = i & 255;
    float v = (r < 64) ? w_qk[r * 256 + c] : w_v[(r - 64) * 256 + c];
    wkvb[i] = (bf16)v;
  }
  if (i < 256 * 256) wtb[i] = (bf16)w_trans[i];
}

// ---------------- transpose x: f32 [b][c][n] -> bf16 [b][n][c] ----------------
__global__ __launch_bounds__(256) void transpose_kernel(const float* __restrict__ x,
                                                        bf16* __restrict__ xTb) {
  __shared__ float t[64][65];
  int b = blockIdx.z, c0 = blockIdx.y * 64, n0 = blockIdx.x * 64;
  int tx = threadIdx.x & 63, ty = threadIdx.x >> 6;
  const float* xp = x + ((size_t)b * CCH + c0) * NN + n0;
#pragma unroll
  for (int j = 0; j < 16; ++j) {
    int cl = ty * 16 + j;
    t[tx][cl] = xp[(size_t)cl * NN + tx];
  }
  __syncthreads();
  bf16* op = xTb + ((size_t)b * NN + n0) * CCH + c0;
#pragma unroll
  for (int j = 0; j < 16; ++j) {
    int nl = ty * 16 + j;
    op[(size_t)nl * CCH + tx] = (bf16)t[nl][tx];
  }
}

// ---------------- kv: K (n-major [n][64]) + sq[n]=|K_n|^2, V = w_v*x + b_v ([c][n]) ----------------
// grid (NN/128, 5, B) = 640 WGs (2.5/CU); block 256; wave w owns n [n0+32w, +32)
__global__ __launch_bounds__(256) void kv_kernel(const bf16* __restrict__ wkvb,
                                                 const bf16* __restrict__ xTb,
                                                 const float* __restrict__ b_v,
                                                 bf16* __restrict__ Knq,
                                                 bf16* __restrict__ V,
                                                 float* __restrict__ sq) {
  int b = blockIdx.z, chunk = blockIdx.y;
  int w = threadIdx.x >> 6, lane = threadIdx.x & 63, lg = lane >> 4, lr = lane & 15;
  int n0 = blockIdx.x * 128 + w * 32;
  int r0 = chunk * 64;
  f32x4 z = {0.f, 0.f, 0.f, 0.f};
  f32x4 acc[4][2];
#pragma unroll
  for (int i = 0; i < 4; ++i)
#pragma unroll
    for (int j = 0; j < 2; ++j) acc[i][j] = z;

#pragma unroll
  for (int ks = 0; ks < 8; ++ks) {
    bf16x8 af[4], bb[2];
#pragma unroll
    for (int t = 0; t < 4; ++t)
      af[t] = *(const bf16x8*)(wkvb + (size_t)(r0 + 16 * t + lr) * 256 + 32 * ks + 8 * lg);
#pragma unroll
    for (int t = 0; t < 2; ++t)
      bb[t] = *(const bf16x8*)(xTb + ((size_t)b * NN + n0 + 16 * t + lr) * CCH + 32 * ks + 8 * lg);
#pragma unroll
    for (int tc = 0; tc < 4; ++tc)
#pragma unroll
      for (int tn = 0; tn < 2; ++tn) acc[tc][tn] = mfma16(af[tc], bb[tn], acc[tc][tn]);
  }

  if (chunk == 0) {
    float sqn[2];
#pragma unroll
    for (int tn = 0; tn < 2; ++tn) {
      int n = n0 + 16 * tn + lr;
#pragma unroll
      for (int tc = 0; tc < 4; ++tc) {
        bf16x4 kb;
#pragma unroll
        for (int r = 0; r < 4; ++r) kb[r] = (bf16)acc[tc][tn][r];
        *(bf16x4*)(Knq + ((size_t)b * NN + n) * CQ + 16 * tc + lg * 4) = kb;
      }
      float s = 0.f;
#pragma unroll
      for (int tc = 0; tc < 4; ++tc)
#pragma unroll
        for (int r = 0; r < 4; ++r) s += acc[tc][tn][r] * acc[tc][tn][r];
      s += __shfl_xor(s, 16);
      s += __shfl_xor(s, 32);
      sqn[tn] = s;
    }
    if (lane < 16) {
#pragma unroll
      for (int tn = 0; tn < 2; ++tn)
        sq[(size_t)b * NN + n0 + 16 * tn + lane] = sqn[tn];
    }
  } else {
#pragma unroll
    for (int tc = 0; tc < 4; ++tc) {
      int c4 = (chunk - 1) * 64 + 16 * tc + lg * 4;
      f32x4 bv = *(const f32x4*)(b_v + c4);
#pragma unroll
      for (int tn = 0; tn < 2; ++tn) {
        int n = n0 + 16 * tn + lr;
#pragma unroll
        for (int r = 0; r < 4; ++r)
          V[((size_t)b * CCH + c4 + r) * NN + n] = (bf16)(acc[tc][tn][r] + bv[r]);
      }
    }
  }
}

// ---------------- rnorm: invr[n] = 1 / sum_m exp(S[n][m] - sq[n]) ----------------
// grid (NN/32, B) = 512 WGs (2/CU); block 256 = 4 waves; wave w owns m-quarter.
__global__ __launch_bounds__(256, 2) void rnorm_kernel(const bf16* __restrict__ Knq,
                                                       const float* __restrict__ sq,
                                                       float* __restrict__ invr) {
  __shared__ float lsl[4][2][16];
  int b = blockIdx.y, n0 = blockIdx.x * 32;
  int w = threadIdx.x >> 6, lane = threadIdx.x & 63, lg = lane >> 4, lr = lane & 15;
  const bf16* Kb = Knq + (size_t)b * NN * CQ;
  bf16x8 a0[2], a1[2];
  f32x4 sh[2];
#pragma unroll
  for (int g = 0; g < 2; ++g) {
    int nr = n0 + 16 * g;
    a0[g] = *(const bf16x8*)(Kb + (size_t)(nr + lr) * CQ + 8 * lg);
    a1[g] = *(const bf16x8*)(Kb + (size_t)(nr + lr) * CQ + 32 + 8 * lg);
    sh[g] = *(const f32x4*)(sq + (size_t)b * NN + nr + lg * 4);
  }
  f32x4 z = {0.f, 0.f, 0.f, 0.f};
  f32x4 ls[2] = {z, z};
  for (int mt = w * (NN / 4); mt < (w + 1) * (NN / 4); mt += 64) {
#pragma unroll
    for (int j = 0; j < 4; ++j) {
      int m0 = mt + 16 * j;
      bf16x8 b0 = *(const bf16x8*)(Kb + (size_t)(m0 + lr) * CQ + 8 * lg);
      bf16x8 b1 = *(const bf16x8*)(Kb + (size_t)(m0 + lr) * CQ + 32 + 8 * lg);
#pragma unroll
      for (int g = 0; g < 2; ++g) {
        f32x4 s = mfma16(a0[g], b0, z);
        s = mfma16(a1[g], b1, s);
#pragma unroll
        for (int r = 0; r < 4; ++r) ls[g][r] += __expf(s[r] - sh[g][r]);
      }
    }
  }
#pragma unroll
  for (int d = 1; d < 16; d <<= 1)
#pragma unroll
    for (int g = 0; g < 2; ++g)
#pragma unroll
      for (int r = 0; r < 4; ++r) ls[g][r] += __shfl_xor(ls[g][r], d);
  if (lr == 0) {
#pragma unroll
    for (int g = 0; g < 2; ++g)
#pragma unroll
      for (int r = 0; r < 4; ++r) lsl[w][g][lg * 4 + r] = ls[g][r];
  }
  __syncthreads();
  if (threadIdx.x < 32) {
    int g = threadIdx.x >> 4, i = threadIdx.x & 15;
    float S = lsl[0][g][i] + lsl[1][g][i] + lsl[2][g][i] + lsl[3][g][i];
    invr[(size_t)b * NN + n0 + 16 * g + i] = 1.0f / S;
  }
}

// ---------------- pv: m-tile 32, 256 thr, 2 WGs/CU, pipelined, swizzled P ----------------
// grid 512 = 2/CU. Wave w: S n-rows [32w,+32) of each 128-window; PV c-rows [64w,+64).
#define SWZ(row, colb) ((colb) ^ (((row)&7) << 4))
__global__ __launch_bounds__(256, 2) void pv_kernel(const bf16* __restrict__ Knq,
                                                    const bf16* __restrict__ V,
                                                    const float* __restrict__ sq,
                                                    const float* __restrict__ invr,
                                                    const bf16* __restrict__ xTb,
                                                    bf16* __restrict__ DTb) {
  __shared__ bf16 P2[2][32][128];  // [buf][m_local][n_local], swizzled cols
  __shared__ float csl[4][32];
  __shared__ float csv[32];
  // XCD remap: 512 WGs; each XCD serves one batch-half (V 2MB + K .5MB L2-local)
  int lin = blockIdx.y * (NN / 32) + blockIdx.x;  // 0..511
  int xcd = lin & 7, slot = lin >> 3;             // slot 0..63
  int b = xcd >> 1;
  int m0 = (((xcd & 1) << 6) | slot) * 32;
  int w = threadIdx.x >> 6, lane = threadIdx.x & 63, lg = lane >> 4, lr = lane & 15;
  const bf16* Kb = Knq + (size_t)b * NN * CQ;
  const bf16* Vb = V + (size_t)b * CCH * NN;
  f32x4 z = {0.f, 0.f, 0.f, 0.f};

  bf16x8 bS[2][2];
#pragma unroll
  for (int tj = 0; tj < 2; ++tj) {
    bS[tj][0] = *(const bf16x8*)(Kb + (size_t)(m0 + 16 * tj + lr) * CQ + 8 * lg);
    bS[tj][1] = *(const bf16x8*)(Kb + (size_t)(m0 + 16 * tj + lr) * CQ + 32 + 8 * lg);
  }

  f32x4 acc[4][2];  // [tc][tj]
#pragma unroll
  for (int i = 0; i < 4; ++i)
#pragma unroll
    for (int j = 0; j < 2; ++j) acc[i][j] = z;
  float cs[2] = {0.f, 0.f};

#define S_PHASE(STEP, BUF)                                                            \
  {                                                                                   \
    _Pragma("unroll") for (int g = 0; g < 2; ++g) {                                   \
      int nr_ = (STEP) * 128 + 32 * w + 16 * g;                                       \
      bf16x8 a0_ = *(const bf16x8*)(Kb + (size_t)(nr_ + lr) * CQ + 8 * lg);           \
      bf16x8 a1_ = *(const bf16x8*)(Kb + (size_t)(nr_ + lr) * CQ + 32 + 8 * lg);      \
      f32x4 sh_ = *(const f32x4*)(sq + (size_t)b * NN + nr_ + lg * 4);                \
      f32x4 ri_ = *(const f32x4*)(invr + (size_t)b * NN + nr_ + lg * 4);              \
      _Pragma("unroll") for (int tj = 0; tj < 2; ++tj) {                              \
        f32x4 s4 = mfma16(a0_, bS[tj][0], z);                                         \
        s4 = mfma16(a1_, bS[tj][1], s4);                                              \
        bf16x4 pb;                                                                    \
        _Pragma("unroll") for (int r = 0; r < 4; ++r) {                               \
          float p_ = __expf(s4[r] - sh_[r]) * ri_[r];                                 \
          cs[tj] += p_;                                                               \
          pb[r] = (bf16)p_;                                                           \
        }                                                                             \
        *(bf16x4*)((char*)&P2[BUF][16 * tj + lr][0] +                                 \
                   SWZ(lr, 2 * (32 * w + 16 * g + 4 * lg))) = pb;                     \
      }                                                                               \
    }                                                                                 \
  }

  S_PHASE(0, 0);
  __syncthreads();

  for (int s = 0; s < NN / 128; ++s) {
    int cur = s & 1;
    int ns = s * 128;
    bf16x8 av[4][4];  // V prefetch: c-rows [64w,+64), issued first (global latency)
#pragma unroll
    for (int ks = 0; ks < 4; ++ks)
#pragma unroll
      for (int tc = 0; tc < 4; ++tc)
        av[ks][tc] = *(const bf16x8*)(Vb + (size_t)(64 * w + 16 * tc + lr) * NN + ns + 32 * ks + 8 * lg);
    bf16x8 bp[4][2];
#pragma unroll
    for (int ks = 0; ks < 4; ++ks)
#pragma unroll
      for (int tj = 0; tj < 2; ++tj)
        bp[ks][tj] = *(const bf16x8*)((char*)&P2[cur][16 * tj + lr][0] +
                                      SWZ(16 * tj + lr, 2 * (32 * ks + 8 * lg)));
    if (s + 1 < NN / 128) S_PHASE(s + 1, cur ^ 1);
#pragma unroll
    for (int ks = 0; ks < 4; ++ks)
#pragma unroll
      for (int tc = 0; tc < 4; ++tc)
#pragma unroll
        for (int tj = 0; tj < 2; ++tj) acc[tc][tj] = mfma16(av[ks][tc], bp[ks][tj], acc[tc][tj]);
    __syncthreads();
  }

  // column sums: reduce per-lane partials over lg, then across waves
#pragma unroll
  for (int tj = 0; tj < 2; ++tj) {
    cs[tj] += __shfl_xor(cs[tj], 16);
    cs[tj] += __shfl_xor(cs[tj], 32);
  }
  if (lane < 16) {
#pragma unroll
    for (int tj = 0; tj < 2; ++tj) csl[w][16 * tj + lane] = cs[tj];
  }
  __syncthreads();
  if (threadIdx.x < 32) {
    int t = threadIdx.x;
    float s = csl[0][t] + csl[1][t] + csl[2][t] + csl[3][t];
    csv[t] = 1.0f / (1e-9f + s);
  }
  __syncthreads();

  // epilogue: DT[m][c] = xT[m][c] - U[c][m]*csv[m]
#pragma unroll
  for (int tj = 0; tj < 2; ++tj) {
    int ml = 16 * tj + lr;
    int m = m0 + ml;
    float ci = csv[ml];
#pragma unroll
    for (int tc = 0; tc < 4; ++tc) {
      int c4 = 64 * w + 16 * tc + lg * 4;
      bf16x4 xv = *(const bf16x4*)(xTb + ((size_t)b * NN + m) * CCH + c4);
      bf16x4 dv;
#pragma unroll
      for (int r = 0; r < 4; ++r) dv[r] = (bf16)((float)xv[r] - acc[tc][tj][r] * ci);
      *(bf16x4*)(DTb + ((size_t)b * NN + m) * CCH + c4) = dv;
    }
  }
}

// ---------------- final: out = ReLU(BN(w_trans * D + b_trans)) ----------------
// grid (NN/32, B) = 512 WGs (2/CU); block 256; wave w owns cout [64w,+64), n-tile 32.
__global__ __launch_bounds__(256) void final_kernel(const bf16* __restrict__ wtb,
                                                    const bf16* __restrict__ DTb,
                                                    const float* __restrict__ b_trans,
                                                    const float* __restrict__ gamma,
                                                    const float* __restrict__ beta,
                                                    const float* __restrict__ mean,
                                                    const float* __restrict__ var,
                                                    float* __restrict__ out) {
  int b = blockIdx.y;
  int w = threadIdx.x >> 6, lane = threadIdx.x & 63, lg = lane >> 4, lr = lane & 15;
  int n0 = blockIdx.x * 32;
  f32x4 z = {0.f, 0.f, 0.f, 0.f};
  f32x4 acc[4][2];
#pragma unroll
  for (int i = 0; i < 4; ++i)
#pragma unroll
    for (int j = 0; j < 2; ++j) acc[i][j] = z;

#pragma unroll
  for (int ks = 0; ks < 8; ++ks) {
    bf16x8 a[4], bb[2];
#pragma unroll
    for (int t = 0; t < 4; ++t)
      a[t] = *(const bf16x8*)(wtb + (size_t)(64 * w + 16 * t + lr) * 256 + 32 * ks + 8 * lg);
#pragma unroll
    for (int t = 0; t < 2; ++t)
      bb[t] = *(const bf16x8*)(DTb + ((size_t)b * NN + n0 + 16 * t + lr) * CCH + 32 * ks + 8 * lg);
#pragma unroll
    for (int tc = 0; tc < 4; ++tc)
#pragma unroll
      for (int tn = 0; tn < 2; ++tn) acc[tc][tn] = mfma16(a[tc], bb[tn], acc[tc][tn]);
  }

#pragma unroll
  for (int tc = 0; tc < 4; ++tc) {
    int c4 = 64 * w + 16 * tc + lg * 4;
    f32x4 bt = *(const f32x4*)(b_trans + c4);
    f32x4 gm = *(const f32x4*)(gamma + c4);
    f32x4 be = *(const f32x4*)(beta + c4);
    f32x4 mn = *(const f32x4*)(mean + c4);
    f32x4 vr = *(const f32x4*)(var + c4);
    f32x4 sc, shv;
#pragma unroll
    for (int r = 0; r < 4; ++r) {
      sc[r] = gm[r] * rsqrtf(vr[r] + 1e-5f);
      shv[r] = be[r] - mn[r] * sc[r];
    }
#pragma unroll
    for (int tn = 0; tn < 2; ++tn) {
      int n = n0 + 16 * tn + lr;
#pragma unroll
      for (int r = 0; r < 4; ++r) {
        float y = (acc[tc][tn][r] + bt[r]) * sc[r] + shv[r];
        out[((size_t)b * CCH + c4 + r) * NN + n] = fmaxf(y, 0.0f);
      }
    }
  }
}

extern "C" void kernel_launch(void* const* d_in, const int* in_sizes, int n_in,
                              void* d_out, int out_size, void* d_ws, size_t ws_size,
                              hipStream_t stream) {
  const float* x = (const float*)d_in[0];
  const float* w_qk = (const float*)d_in[1];
  const float* w_v = (const float*)d_in[2];
  const float* b_v = (const float*)d_in[3];
  const float* w_trans = (const float*)d_in[4];
  const float* b_trans = (const float*)d_in[5];
  const float* gamma = (const float*)d_in[6];
  const float* beta = (const float*)d_in[7];
  const float* mean = (const float*)d_in[8];
  const float* var = (const float*)d_in[9];
  float* out = (float*)d_out;

  char* p = (char*)d_ws;
  bf16* wkvb = (bf16*)p; p += (size_t)320 * 256 * 2;
  bf16* wtb = (bf16*)p;  p += (size_t)256 * 256 * 2;
  bf16* xTb = (bf16*)p;  p += (size_t)BATCH * NN * CCH * 2;
  bf16* Knq = (bf16*)p;  p += (size_t)BATCH * NN * CQ * 2;
  bf16* V = (bf16*)p;    p += (size_t)BATCH * CCH * NN * 2;
  float* sq = (float*)p;   p += (size_t)BATCH * NN * 4;
  float* invr = (float*)p; p += (size_t)BATCH * NN * 4;
  bf16* DTb = (bf16*)p;  p += (size_t)BATCH * NN * CCH * 2;

  hipLaunchKernelGGL(prep_kernel, dim3(320), dim3(256), 0, stream, w_qk, w_v, w_trans, wkvb, wtb);
  hipLaunchKernelGGL(transpose_kernel, dim3(NN / 64, CCH / 64, BATCH), dim3(256), 0, stream, x, xTb);
  hipLaunchKernelGGL(kv_kernel, dim3(NN / 128, 5, BATCH), dim3(256), 0, stream, wkvb, xTb, b_v, Knq, V, sq);
  hipLaunchKernelGGL(rnorm_kernel, dim3(NN / 32, BATCH), dim3(256), 0, stream, Knq, sq, invr);
  hipLaunchKernelGGL(pv_kernel, dim3(NN / 32, BATCH), dim3(256), 0, stream, Knq, V, sq, invr, xTb, DTb);
  hipLaunchKernelGGL(final_kernel, dim3(NN / 32, BATCH), dim3(256), 0, stream, wtb, DTb, b_trans, gamma, beta, mean, var, out);
}

// Round 8
// 265.181 us; speedup vs baseline: 1.3153x; 1.3153x over previous
//
#include <hip/hip_runtime.h>

#define BATCH 4
#define CCH 256
#define NN 4096
#define CQ 64

typedef __bf16 bf16;
typedef __bf16 bf16x4 __attribute__((ext_vector_type(4)));
typedef __bf16 bf16x8 __attribute__((ext_vector_type(8)));
typedef float f32x4 __attribute__((ext_vector_type(4)));

static __device__ __forceinline__ f32x4 mfma16(bf16x8 a, bf16x8 b, f32x4 c) {
  return __builtin_amdgcn_mfma_f32_16x16x32_bf16(a, b, c, 0, 0, 0);
}

// ---------------- prep: convert weights to bf16 ----------------
__global__ __launch_bounds__(256) void prep_kernel(const float* __restrict__ w_qk,
                                                   const float* __restrict__ w_v,
                                                   const float* __restrict__ w_trans,
                                                   bf16* __restrict__ wkvb,
                                                   bf16* __restrict__ wtb) {
  int i = blockIdx.x * 256 + threadIdx.x;
  if (i < 320 * 256) {
    int r = i >> 8, c = i & 255;
    float v = (r < 64) ? w_qk[r * 256 + c] : w_v[(r - 64) * 256 + c];
    wkvb[i] = (bf16)v;
  }
  if (i < 256 * 256) wtb[i] = (bf16)w_trans[i];
}

// ---------------- transpose x: f32 [b][c][n] -> bf16 [b][n][c] ----------------
__global__ __launch_bounds__(256) void transpose_kernel(const float* __restrict__ x,
                                                        bf16* __restrict__ xTb) {
  __shared__ float t[64][65];
  int b = blockIdx.z, c0 = blockIdx.y * 64, n0 = blockIdx.x * 64;
  int tx = threadIdx.x & 63, ty = threadIdx.x >> 6;
  const float* xp = x + ((size_t)b * CCH + c0) * NN + n0;
#pragma unroll
  for (int j = 0; j < 16; ++j) {
    int cl = ty * 16 + j;
    t[tx][cl] = xp[(size_t)cl * NN + tx];
  }
  __syncthreads();
  bf16* op = xTb + ((size_t)b * NN + n0) * CCH + c0;
#pragma unroll
  for (int j = 0; j < 16; ++j) {
    int nl = ty * 16 + j;
    op[(size_t)nl * CCH + tx] = (bf16)t[nl][tx];
  }
}

// ---------------- kv: K (n-major [n][64]) + sq[n]=|K_n|^2, V = w_v*x + b_v ([c][n]) ----------------
// grid (NN/128, 5, B) = 640 WGs (2.5/CU); block 256; wave w owns n [n0+32w, +32)
__global__ __launch_bounds__(256) void kv_kernel(const bf16* __restrict__ wkvb,
                                                 const bf16* __restrict__ xTb,
                                                 const float* __restrict__ b_v,
                                                 bf16* __restrict__ Knq,
                                                 bf16* __restrict__ V,
                                                 float* __restrict__ sq) {
  int b = blockIdx.z, chunk = blockIdx.y;
  int w = threadIdx.x >> 6, lane = threadIdx.x & 63, lg = lane >> 4, lr = lane & 15;
  int n0 = blockIdx.x * 128 + w * 32;
  int r0 = chunk * 64;
  f32x4 z = {0.f, 0.f, 0.f, 0.f};
  f32x4 acc[4][2];
#pragma unroll
  for (int i = 0; i < 4; ++i)
#pragma unroll
    for (int j = 0; j < 2; ++j) acc[i][j] = z;

#pragma unroll
  for (int ks = 0; ks < 8; ++ks) {
    bf16x8 af[4], bb[2];
#pragma unroll
    for (int t = 0; t < 4; ++t)
      af[t] = *(const bf16x8*)(wkvb + (size_t)(r0 + 16 * t + lr) * 256 + 32 * ks + 8 * lg);
#pragma unroll
    for (int t = 0; t < 2; ++t)
      bb[t] = *(const bf16x8*)(xTb + ((size_t)b * NN + n0 + 16 * t + lr) * CCH + 32 * ks + 8 * lg);
#pragma unroll
    for (int tc = 0; tc < 4; ++tc)
#pragma unroll
      for (int tn = 0; tn < 2; ++tn) acc[tc][tn] = mfma16(af[tc], bb[tn], acc[tc][tn]);
  }

  if (chunk == 0) {
    float sqn[2];
#pragma unroll
    for (int tn = 0; tn < 2; ++tn) {
      int n = n0 + 16 * tn + lr;
#pragma unroll
      for (int tc = 0; tc < 4; ++tc) {
        bf16x4 kb;
#pragma unroll
        for (int r = 0; r < 4; ++r) kb[r] = (bf16)acc[tc][tn][r];
        *(bf16x4*)(Knq + ((size_t)b * NN + n) * CQ + 16 * tc + lg * 4) = kb;
      }
      float s = 0.f;
#pragma unroll
      for (int tc = 0; tc < 4; ++tc)
#pragma unroll
        for (int r = 0; r < 4; ++r) s += acc[tc][tn][r] * acc[tc][tn][r];
      s += __shfl_xor(s, 16);
      s += __shfl_xor(s, 32);
      sqn[tn] = s;
    }
    if (lane < 16) {
#pragma unroll
      for (int tn = 0; tn < 2; ++tn)
        sq[(size_t)b * NN + n0 + 16 * tn + lane] = sqn[tn];
    }
  } else {
#pragma unroll
    for (int tc = 0; tc < 4; ++tc) {
      int c4 = (chunk - 1) * 64 + 16 * tc + lg * 4;
      f32x4 bv = *(const f32x4*)(b_v + c4);
#pragma unroll
      for (int tn = 0; tn < 2; ++tn) {
        int n = n0 + 16 * tn + lr;
#pragma unroll
        for (int r = 0; r < 4; ++r)
          V[((size_t)b * CCH + c4 + r) * NN + n] = (bf16)(acc[tc][tn][r] + bv[r]);
      }
    }
  }
}

// ---------------- rnorm: invr[n] = 1 / sum_m exp(S[n][m] - sq[n]) ----------------
// grid (NN/32, B) = 512 WGs (2/CU); block 256 = 4 waves; wave w owns m-quarter.
__global__ __launch_bounds__(256, 2) void rnorm_kernel(const bf16* __restrict__ Knq,
                                                       const float* __restrict__ sq,
                                                       float* __restrict__ invr) {
  __shared__ float lsl[4][2][16];
  int b = blockIdx.y, n0 = blockIdx.x * 32;
  int w = threadIdx.x >> 6, lane = threadIdx.x & 63, lg = lane >> 4, lr = lane & 15;
  const bf16* Kb = Knq + (size_t)b * NN * CQ;
  bf16x8 a0[2], a1[2];
  f32x4 sh[2];
#pragma unroll
  for (int g = 0; g < 2; ++g) {
    int nr = n0 + 16 * g;
    a0[g] = *(const bf16x8*)(Kb + (size_t)(nr + lr) * CQ + 8 * lg);
    a1[g] = *(const bf16x8*)(Kb + (size_t)(nr + lr) * CQ + 32 + 8 * lg);
    sh[g] = *(const f32x4*)(sq + (size_t)b * NN + nr + lg * 4);
  }
  f32x4 z = {0.f, 0.f, 0.f, 0.f};
  f32x4 ls[2] = {z, z};
  for (int mt = w * (NN / 4); mt < (w + 1) * (NN / 4); mt += 64) {
#pragma unroll
    for (int j = 0; j < 4; ++j) {
      int m0 = mt + 16 * j;
      bf16x8 b0 = *(const bf16x8*)(Kb + (size_t)(m0 + lr) * CQ + 8 * lg);
      bf16x8 b1 = *(const bf16x8*)(Kb + (size_t)(m0 + lr) * CQ + 32 + 8 * lg);
#pragma unroll
      for (int g = 0; g < 2; ++g) {
        f32x4 s = mfma16(a0[g], b0, z);
        s = mfma16(a1[g], b1, s);
#pragma unroll
        for (int r = 0; r < 4; ++r) ls[g][r] += __expf(s[r] - sh[g][r]);
      }
    }
  }
#pragma unroll
  for (int d = 1; d < 16; d <<= 1)
#pragma unroll
    for (int g = 0; g < 2; ++g)
#pragma unroll
      for (int r = 0; r < 4; ++r) ls[g][r] += __shfl_xor(ls[g][r], d);
  if (lr == 0) {
#pragma unroll
    for (int g = 0; g < 2; ++g)
#pragma unroll
      for (int r = 0; r < 4; ++r) lsl[w][g][lg * 4 + r] = ls[g][r];
  }
  __syncthreads();
  if (threadIdx.x < 32) {
    int g = threadIdx.x >> 4, i = threadIdx.x & 15;
    float S = lsl[0][g][i] + lsl[1][g][i] + lsl[2][g][i] + lsl[3][g][i];
    invr[(size_t)b * NN + n0 + 16 * g + i] = 1.0f / S;
  }
}

// ---------------- pv: m-tile 64, c-split 2, 8 waves, 2 WGs/CU ----------------
// grid 512 = (64 m-tiles x 2 c-halves x 4 b), XCD-remapped. Wave w: S n-rows [16w,+16)
// of each 128-window; PV c-rows c0+16w+lr (16 per wave).
#define SWZ(row, colb) ((colb) ^ (((row)&7) << 4))
__global__ __launch_bounds__(512, 4) void pv_kernel(const bf16* __restrict__ Knq,
                                                    const bf16* __restrict__ V,
                                                    const float* __restrict__ sq,
                                                    const float* __restrict__ invr,
                                                    const bf16* __restrict__ xTb,
                                                    bf16* __restrict__ DTb) {
  __shared__ bf16 P2[2][64][128];  // [buf][m_local][n_local], swizzled
  __shared__ float csl[8][64];
  __shared__ float csv[64];
  int lin = blockIdx.x;                 // 0..511
  int xcd = lin & 7, slot = lin >> 3;   // slot 0..63
  int b = xcd >> 1;                     // 2 XCDs per batch
  int m0 = (((xcd & 1) << 5) | (slot & 31)) * 64;
  int c0 = (slot >> 5) * 128;
  int w = threadIdx.x >> 6, lane = threadIdx.x & 63, lg = lane >> 4, lr = lane & 15;
  int nrw = 16 * w;
  const bf16* Kb = Knq + (size_t)b * NN * CQ;
  const bf16* Vb = V + (size_t)b * CCH * NN;
  f32x4 z = {0.f, 0.f, 0.f, 0.f};

  bf16x8 bS[4][2];
#pragma unroll
  for (int tj = 0; tj < 4; ++tj) {
    bS[tj][0] = *(const bf16x8*)(Kb + (size_t)(m0 + 16 * tj + lr) * CQ + 8 * lg);
    bS[tj][1] = *(const bf16x8*)(Kb + (size_t)(m0 + 16 * tj + lr) * CQ + 32 + 8 * lg);
  }

  f32x4 acc[4];  // [tj]; lane holds U[c = c0+16w+4lg+r][m = m0+16tj+lr]
#pragma unroll
  for (int j = 0; j < 4; ++j) acc[j] = z;
  float cs[4] = {0.f, 0.f, 0.f, 0.f};

  // S_PHASE(WIN -> BUF): loads K rows for this wave's 16 n-rows of window WIN,
  // computes P, accumulates cs, writes swizzled P2[BUF].
#define S_PHASE(WIN, BUF)                                                             \
  {                                                                                   \
    int nr_ = (WIN) * 128 + nrw;                                                      \
    bf16x8 k0_ = *(const bf16x8*)(Kb + (size_t)(nr_ + lr) * CQ + 8 * lg);             \
    bf16x8 k1_ = *(const bf16x8*)(Kb + (size_t)(nr_ + lr) * CQ + 32 + 8 * lg);        \
    f32x4 sh_ = *(const f32x4*)(sq + (size_t)b * NN + nr_ + lg * 4);                  \
    f32x4 ri_ = *(const f32x4*)(invr + (size_t)b * NN + nr_ + lg * 4);                \
    _Pragma("unroll") for (int tj = 0; tj < 4; ++tj) {                                \
      f32x4 s4 = mfma16(k0_, bS[tj][0], z);                                           \
      s4 = mfma16(k1_, bS[tj][1], s4);                                                \
      bf16x4 pb;                                                                      \
      _Pragma("unroll") for (int r = 0; r < 4; ++r) {                                 \
        float p_ = __expf(s4[r] - sh_[r]) * ri_[r];                                   \
        cs[tj] += p_;                                                                 \
        pb[r] = (bf16)p_;                                                             \
      }                                                                               \
      *(bf16x4*)((char*)&P2[BUF][16 * tj + lr][0] + SWZ(lr, 2 * (nrw + 4 * lg))) = pb; \
    }                                                                                 \
  }

  // PV_BODY(BUF, NS): V-prefetch for window NS, then per-ks {4 ds_read, 4 mfma}.
#define PV_BODY(BUF, NS)                                                              \
  {                                                                                   \
    bf16x8 av[4];                                                                     \
    _Pragma("unroll") for (int ks = 0; ks < 4; ++ks)                                  \
      av[ks] = *(const bf16x8*)(Vb + (size_t)(c0 + 16 * w + lr) * NN + (NS) * 128 +   \
                                32 * ks + 8 * lg);                                    \
    _Pragma("unroll") for (int ks = 0; ks < 4; ++ks) {                                \
      bf16x8 bp[4];                                                                   \
      _Pragma("unroll") for (int tj = 0; tj < 4; ++tj)                                \
        bp[tj] = *(const bf16x8*)((char*)&P2[BUF][16 * tj + lr][0] +                  \
                                  SWZ(16 * tj + lr, 2 * (32 * ks + 8 * lg)));         \
      _Pragma("unroll") for (int tj = 0; tj < 4; ++tj)                                \
        acc[tj] = mfma16(av[ks], bp[tj], acc[tj]);                                    \
    }                                                                                 \
  }

  S_PHASE(0, 0);
  __syncthreads();
  for (int s2 = 0; s2 < 15; ++s2) {
    int se = 2 * s2;
    PV_BODY(0, se);
    S_PHASE(se + 1, 1);
    __syncthreads();
    PV_BODY(1, se + 1);
    S_PHASE(se + 2, 0);
    __syncthreads();
  }
  PV_BODY(0, 30);
  S_PHASE(31, 1);
  __syncthreads();
  PV_BODY(1, 31);

  // column sums: reduce over lg (shfl), then across 8 waves (LDS)
#pragma unroll
  for (int tj = 0; tj < 4; ++tj) {
    cs[tj] += __shfl_xor(cs[tj], 16);
    cs[tj] += __shfl_xor(cs[tj], 32);
  }
  if (lane < 16) {
#pragma unroll
    for (int tj = 0; tj < 4; ++tj) csl[w][16 * tj + lane] = cs[tj];
  }
  __syncthreads();
  if (threadIdx.x < 64) {
    int t = threadIdx.x;
    float s = 0.f;
#pragma unroll
    for (int ww = 0; ww < 8; ++ww) s += csl[ww][t];
    csv[t] = 1.0f / (1e-9f + s);
  }
  __syncthreads();

  // epilogue: DT[m][c] = xT[m][c] - U[c][m]*csv[m]   (this WG's c-half only)
#pragma unroll
  for (int tj = 0; tj < 4; ++tj) {
    int ml = 16 * tj + lr;
    int m = m0 + ml;
    float ci = csv[ml];
    int c4 = c0 + 16 * w + 4 * lg;
    bf16x4 xv = *(const bf16x4*)(xTb + ((size_t)b * NN + m) * CCH + c4);
    bf16x4 dv;
#pragma unroll
    for (int r = 0; r < 4; ++r) dv[r] = (bf16)((float)xv[r] - acc[tj][r] * ci);
    *(bf16x4*)(DTb + ((size_t)b * NN + m) * CCH + c4) = dv;
  }
}

// ---------------- final: out = ReLU(BN(w_trans * D + b_trans)) ----------------
// grid (NN/32, B) = 512 WGs (2/CU); block 256; wave w owns cout [64w,+64), n-tile 32.
__global__ __launch_bounds__(256) void final_kernel(const bf16* __restrict__ wtb,
                                                    const bf16* __restrict__ DTb,
                                                    const float* __restrict__ b_trans,
                                                    const float* __restrict__ gamma,
                                                    const float* __restrict__ beta,
                                                    const float* __restrict__ mean,
                                                    const float* __restrict__ var,
                                                    float* __restrict__ out) {
  int b = blockIdx.y;
  int w = threadIdx.x >> 6, lane = threadIdx.x & 63, lg = lane >> 4, lr = lane & 15;
  int n0 = blockIdx.x * 32;
  f32x4 z = {0.f, 0.f, 0.f, 0.f};
  f32x4 acc[4][2];
#pragma unroll
  for (int i = 0; i < 4; ++i)
#pragma unroll
    for (int j = 0; j < 2; ++j) acc[i][j] = z;

#pragma unroll
  for (int ks = 0; ks < 8; ++ks) {
    bf16x8 a[4], bb[2];
#pragma unroll
    for (int t = 0; t < 4; ++t)
      a[t] = *(const bf16x8*)(wtb + (size_t)(64 * w + 16 * t + lr) * 256 + 32 * ks + 8 * lg);
#pragma unroll
    for (int t = 0; t < 2; ++t)
      bb[t] = *(const bf16x8*)(DTb + ((size_t)b * NN + n0 + 16 * t + lr) * CCH + 32 * ks + 8 * lg);
#pragma unroll
    for (int tc = 0; tc < 4; ++tc)
#pragma unroll
      for (int tn = 0; tn < 2; ++tn) acc[tc][tn] = mfma16(a[tc], bb[tn], acc[tc][tn]);
  }

#pragma unroll
  for (int tc = 0; tc < 4; ++tc) {
    int c4 = 64 * w + 16 * tc + lg * 4;
    f32x4 bt = *(const f32x4*)(b_trans + c4);
    f32x4 gm = *(const f32x4*)(gamma + c4);
    f32x4 be = *(const f32x4*)(beta + c4);
    f32x4 mn = *(const f32x4*)(mean + c4);
    f32x4 vr = *(const f32x4*)(var + c4);
    f32x4 sc, shv;
#pragma unroll
    for (int r = 0; r < 4; ++r) {
      sc[r] = gm[r] * rsqrtf(vr[r] + 1e-5f);
      shv[r] = be[r] - mn[r] * sc[r];
    }
#pragma unroll
    for (int tn = 0; tn < 2; ++tn) {
      int n = n0 + 16 * tn + lr;
#pragma unroll
      for (int r = 0; r < 4; ++r) {
        float y = (acc[tc][tn][r] + bt[r]) * sc[r] + shv[r];
        out[((size_t)b * CCH + c4 + r) * NN + n] = fmaxf(y, 0.0f);
      }
    }
  }
}

extern "C" void kernel_launch(void* const* d_in, const int* in_sizes, int n_in,
                              void* d_out, int out_size, void* d_ws, size_t ws_size,
                              hipStream_t stream) {
  const float* x = (const float*)d_in[0];
  const float* w_qk = (const float*)d_in[1];
  const float* w_v = (const float*)d_in[2];
  const float* b_v = (const float*)d_in[3];
  const float* w_trans = (const float*)d_in[4];
  const float* b_trans = (const float*)d_in[5];
  const float* gamma = (const float*)d_in[6];
  const float* beta = (const float*)d_in[7];
  const float* mean = (const float*)d_in[8];
  const float* var = (const float*)d_in[9];
  float* out = (float*)d_out;

  char* p = (char*)d_ws;
  bf16* wkvb = (bf16*)p; p += (size_t)320 * 256 * 2;
  bf16* wtb = (bf16*)p;  p += (size_t)256 * 256 * 2;
  bf16* xTb = (bf16*)p;  p += (size_t)BATCH * NN * CCH * 2;
  bf16* Knq = (bf16*)p;  p += (size_t)BATCH * NN * CQ * 2;
  bf16* V = (bf16*)p;    p += (size_t)BATCH * CCH * NN * 2;
  float* sq = (float*)p;   p += (size_t)BATCH * NN * 4;
  float* invr = (float*)p; p += (size_t)BATCH * NN * 4;
  bf16* DTb = (bf16*)p;  p += (size_t)BATCH * NN * CCH * 2;

  hipLaunchKernelGGL(prep_kernel, dim3(320), dim3(256), 0, stream, w_qk, w_v, w_trans, wkvb, wtb);
  hipLaunchKernelGGL(transpose_kernel, dim3(NN / 64, CCH / 64, BATCH), dim3(256), 0, stream, x, xTb);
  hipLaunchKernelGGL(kv_kernel, dim3(NN / 128, 5, BATCH), dim3(256), 0, stream, wkvb, xTb, b_v, Knq, V, sq);
  hipLaunchKernelGGL(rnorm_kernel, dim3(NN / 32, BATCH), dim3(256), 0, stream, Knq, sq, invr);
  hipLaunchKernelGGL(pv_kernel, dim3(512), dim3(512), 0, stream, Knq, V, sq, invr, xTb, DTb);
  hipLaunchKernelGGL(final_kernel, dim3(NN / 32, BATCH), dim3(256), 0, stream, wtb, DTb, b_trans, gamma, beta, mean, var, out);
}